// Round 11
// baseline (5277.596 us; speedup 1.0000x reference)
//
#include <hip/hip_runtime.h>

#define TT 64
#define BB 4096
#define HH 256
#define BM 8              // batch elements per block
#define NBLK (BB / BM)    // 512 blocks -> 2 blocks/CU, 8 waves/CU

// d_ws layout (byte offsets)
#define WS_WHT_B   0u              // W_h^T  f32, 256KB
#define WS_WH2T_B  262144u         // W_h2^T f32, 256KB
#define WS_EMB_B   524288u         // emb f32, 256B
#define WS_REC_B   1048576u        // rec f32 [T,B,4], 4MB
#define WS_SG1_B   6291456u        // spike floats layer1 [block][256][8] f32, 4MB
#define WS_SG2_B   10485760u       // spike floats layer2, 4MB   (total 14MB)

__device__ __forceinline__ float clip01f(float v) {
    return fminf(fmaxf(v, 0.0f), 1.0f);
}

__global__ __launch_bounds__(64) void setup_emb_kernel(float* __restrict__ emb) {
    int i = threadIdx.x;
    const double sigma = 64.0 / 10.0;
    const double c = 32.0;
    double d = ((double)i - c) / sigma;
    double e = exp(-0.5 * (d * d));
    double d0 = (0.0 - c) / sigma;
    double emin = exp(-0.5 * (d0 * d0));
    emb[i] = (float)((e - emin) / (1.0 - emin));   // e.max() = exp(0) = 1
}

__global__ __launch_bounds__(256) void transpose_kernel(const float* __restrict__ src,
                                                        float* __restrict__ dst) {
    __shared__ float tile[32][33];
    int tx = threadIdx.x & 31, ty = threadIdx.x >> 5;
    int bx = blockIdx.x, by = blockIdx.y;
#pragma unroll
    for (int i = 0; i < 32; i += 8)
        tile[ty + i][tx] = src[(by * 32 + ty + i) * HH + bx * 32 + tx];
    __syncthreads();
#pragma unroll
    for (int i = 0; i < 32; i += 8)
        dst[(bx * 32 + ty + i) * HH + by * 32 + tx] = tile[tx][ty + i];
}

// Dense gated matvec, spikes via GLOBAL scratch (L1-broadcast), weights via
// nontemporal loads (no L1 allocate -> spike lines stay resident).
// acc[b] = sum_{k=0..255 asc} fmaf(s[k][b], WT[k*256+n], acc[b]),
// s in {1.0f,0.0f}: fmaf(0,w,a)==a exact, fmaf(1,w,a)==RN(a+w) ->
// bit-identical to the verified ascending chain (validated in R10).
__device__ __forceinline__ void dense_accum_g(const float* __restrict__ WT, int n,
                                              const float* __restrict__ sG, float acc[BM]) {
    const float* Wp = WT + n;
#pragma unroll 8
    for (int k = 0; k < HH; ++k) {
        float wv = __builtin_nontemporal_load(Wp + (k << 8));   // coalesced 256B/wave, L2
        float4 sa = *(const float4*)(sG + (k << 3));            // same addr all lanes: L1 broadcast
        float4 sb = *(const float4*)(sG + (k << 3) + 4);
        acc[0] = fmaf(sa.x, wv, acc[0]);
        acc[1] = fmaf(sa.y, wv, acc[1]);
        acc[2] = fmaf(sa.z, wv, acc[2]);
        acc[3] = fmaf(sa.w, wv, acc[3]);
        acc[4] = fmaf(sb.x, wv, acc[4]);
        acc[5] = fmaf(sb.y, wv, acc[5]);
        acc[6] = fmaf(sb.z, wv, acc[6]);
        acc[7] = fmaf(sb.w, wv, acc[7]);
    }
}

__global__ __launch_bounds__(256, 2) void snn_main_kernel(
    const float* __restrict__ x,
    const float* __restrict__ W_in, const float* __restrict__ b_in,
    const float* __restrict__ beta_in, const float* __restrict__ thr_in,
    const float* __restrict__ b_h, const float* __restrict__ beta_h, const float* __restrict__ thr_h,
    const float* __restrict__ b_h2, const float* __restrict__ beta_h2, const float* __restrict__ thr_h2,
    const float* __restrict__ W_out, const float* __restrict__ b_out, const float* __restrict__ beta_out,
    const float* __restrict__ WhT, const float* __restrict__ Wh2T,
    const float* __restrict__ emb, float* __restrict__ rec,
    float* __restrict__ sG1, float* __restrict__ sG2)
{
#pragma clang fp contract(off)   // all contraction EXPLICIT via fmaf below
    const int tid = threadIdx.x;
    const int n = tid;                  // thread = neuron
    const int w = tid >> 6, lane = tid & 63;
    const int b0 = blockIdx.x * BM;

    float* sG1b = sG1 + (size_t)blockIdx.x * (HH * BM);   // [256][8] f32, 8KB
    float* sG2b = sG2 + (size_t)blockIdx.x * (HH * BM);

    __shared__ unsigned long long M3L[4][BM];
    __shared__ float WoutS[2][HH];
    WoutS[0][n] = W_out[n];
    WoutS[1][n] = W_out[HH + n];

    float bi  = b_in[n];
    float bt1 = clip01f(beta_in[n]), th1 = thr_in[n];
    float bh  = b_h[n];
    float bt2 = clip01f(beta_h[n]),  th2 = thr_h[n];
    float bh2v = b_h2[n];
    float bt3 = clip01f(beta_h2[n]), th3 = thr_h2[n];
    float wi0 = W_in[n * 3], wi1 = W_in[n * 3 + 1], wi2 = W_in[n * 3 + 2];

    const int ob = (tid >> 1) & (BM - 1);   // output-stage batch (wave 0, tid<2*BM)
    const int oo = tid & 1;                 // output channel
    float bto = clip01f(beta_out[oo]);
    float bo  = b_out[oo];

    float m1[BM], m2[BM], m4[BM], acc[BM];
#pragma unroll
    for (int b = 0; b < BM; ++b) { m1[b] = 0.f; m2[b] = 0.f; m4[b] = 0.f; }
    float m3s = 0.f;

    for (int t = 0; t < TT; ++t) {
        float et = emb[t];
        float xf[BM * 3];
        const float4* xp = (const float4*)(x + (size_t)(t * BB + b0) * 3);
#pragma unroll
        for (int i = 0; i < (BM * 3) / 4; ++i) *(float4*)(xf + 4 * i) = xp[i];

        // ---- layer 1: ascending-k fma dot, bias after; contracted LIF update ----
        {
            float sf[BM];
#pragma unroll
            for (int b = 0; b < BM; ++b) {
                float xe0 = xf[b * 3 + 0] * et;
                float xe1 = xf[b * 3 + 1] * et;
                float xe2 = xf[b * 3 + 2] * et;
                float a1 = xe0 * wi0;                  // == fma(xe0,wi0,0)
                a1 = fmaf(xe1, wi1, a1);
                a1 = fmaf(xe2, wi2, a1);
                float cur = a1 + bi;
                float rf = ((m1[b] - th1) > 0.f) ? 1.f : 0.f;   // reset from PREVIOUS mem
                float mm = fmaf(bt1, m1[b], cur);      // contracted: beta*m + cur
                mm = fmaf(-rf, th1, mm);               // contracted: - reset*thr
                m1[b] = mm;
                sf[b] = ((mm - th1) > 0.f) ? 1.f : 0.f;
            }
            *(float4*)(sG1b + n * BM)     = make_float4(sf[0], sf[1], sf[2], sf[3]);
            *(float4*)(sG1b + n * BM + 4) = make_float4(sf[4], sf[5], sf[6], sf[7]);
        }
        __syncthreads();   // drains vmcnt -> sG1 visible block-wide

        // ---- layer 2: dense gated fma over sG1 ----
#pragma unroll
        for (int b = 0; b < BM; ++b) acc[b] = 0.f;
        dense_accum_g(WhT, n, sG1b, acc);
        {
            float sf[BM];
#pragma unroll
            for (int b = 0; b < BM; ++b) {
                float cur = acc[b] + bh;
                float rf = ((m2[b] - th2) > 0.f) ? 1.f : 0.f;
                float mm = fmaf(bt2, m2[b], cur);
                mm = fmaf(-rf, th2, mm);
                m2[b] = mm;
                sf[b] = ((mm - th2) > 0.f) ? 1.f : 0.f;
            }
            *(float4*)(sG2b + n * BM)     = make_float4(sf[0], sf[1], sf[2], sf[3]);
            *(float4*)(sG2b + n * BM + 4) = make_float4(sf[4], sf[5], sf[6], sf[7]);
        }
        __syncthreads();

        // ---- layer 3: dense gated fma over sG2; ballot masks for li_out ----
#pragma unroll
        for (int b = 0; b < BM; ++b) acc[b] = 0.f;
        dense_accum_g(Wh2T, n, sG2b, acc);
        {
            bool s3[BM];
#pragma unroll
            for (int b = 0; b < BM; ++b) {
                float cur = acc[b] + bh2v;
                float rf = ((m4[b] - th3) > 0.f) ? 1.f : 0.f;
                float mm = fmaf(bt3, m4[b], cur);
                mm = fmaf(-rf, th3, mm);
                m4[b] = mm;
                s3[b] = (mm - th3) > 0.f;
            }
#pragma unroll
            for (int b = 0; b < BM; ++b) {
                unsigned long long mk = __ballot(s3[b]);
                if (lane == 0) M3L[w][b] = mk;
            }
        }
        __syncthreads();

        // ---- li_out (verified R8 form): ascending active-only sum;
        //      m3 = fma(beta_out, m3, dot) + b_out ----
        if (w == 0) {
            float p = 0.f;
#pragma unroll
            for (int w2 = 0; w2 < 4; ++w2) {
                unsigned long long mk = M3L[w2][ob];
                const float* wrow = &WoutS[oo][w2 << 6];
                while (mk) {
                    int l = __builtin_ctzll(mk); mk &= mk - 1;
                    p = p + wrow[l];
                }
            }
            float mm3 = fmaf(bto, m3s, p);
            mm3 = mm3 + bo;
            m3s = mm3;
            float spk = ((m3s - 1.0f) > 0.f) ? 1.f : 0.f;
            float om3 = __shfl_xor(m3s, 1, 64);
            float osp = __shfl_xor(spk, 1, 64);
            if (tid < 2 * BM && oo == 0) {         // rec[t, b0+ob, :] = {spk0, spk1, m30, m31}
                *(float4*)(rec + ((size_t)t * BB + b0 + ob) * 4) =
                    make_float4(spk, osp, m3s, om3);
            }
        }
        // M3L rewritten only after next iteration's 2nd barrier -> wave0 done by then.
    }
}

// out[r,o] = (ascending-k fma dot) + b_pred[o]   (gemm form)
__global__ __launch_bounds__(256) void pred_kernel(
    const float* __restrict__ rec, const float* __restrict__ W_pred,
    const float* __restrict__ b_pred, float* __restrict__ out)
{
#pragma clang fp contract(off)
    int r = blockIdx.x * 256 + threadIdx.x;   // 0..4095
    const float* f = rec + (size_t)r * 256;
    float a0 = 0.f, a1 = 0.f;
#pragma unroll 4
    for (int c = 0; c < 256; ++c) {
        float v = f[c];
        a0 = fmaf(v, W_pred[c], a0);
        a1 = fmaf(v, W_pred[256 + c], a1);
    }
    out[r * 2 + 0] = a0 + b_pred[0];
    out[r * 2 + 1] = a1 + b_pred[1];
}

extern "C" void kernel_launch(void* const* d_in, const int* in_sizes, int n_in,
                              void* d_out, int out_size, void* d_ws, size_t ws_size,
                              hipStream_t stream)
{
    const float* x        = (const float*)d_in[0];
    const float* W_in     = (const float*)d_in[1];
    const float* b_in     = (const float*)d_in[2];
    const float* beta_in  = (const float*)d_in[3];
    const float* thr_in   = (const float*)d_in[4];
    const float* W_h      = (const float*)d_in[5];
    const float* b_h      = (const float*)d_in[6];
    const float* beta_h   = (const float*)d_in[7];
    const float* thr_h    = (const float*)d_in[8];
    const float* W_h2     = (const float*)d_in[9];
    const float* b_h2     = (const float*)d_in[10];
    const float* beta_h2  = (const float*)d_in[11];
    const float* thr_h2   = (const float*)d_in[12];
    const float* W_out    = (const float*)d_in[13];
    const float* b_out    = (const float*)d_in[14];
    const float* beta_out = (const float*)d_in[15];
    const float* W_pred   = (const float*)d_in[16];
    const float* b_pred   = (const float*)d_in[17];

    char* ws = (char*)d_ws;
    float* WhT  = (float*)(ws + WS_WHT_B);
    float* Wh2T = (float*)(ws + WS_WH2T_B);
    float* emb  = (float*)(ws + WS_EMB_B);
    float* rec  = (float*)(ws + WS_REC_B);
    float* sG1  = (float*)(ws + WS_SG1_B);
    float* sG2  = (float*)(ws + WS_SG2_B);

    dim3 tgrid(8, 8);
    transpose_kernel<<<tgrid, 256, 0, stream>>>(W_h, WhT);
    transpose_kernel<<<tgrid, 256, 0, stream>>>(W_h2, Wh2T);
    setup_emb_kernel<<<1, 64, 0, stream>>>(emb);

    snn_main_kernel<<<NBLK, 256, 0, stream>>>(
        x, W_in, b_in, beta_in, thr_in,
        b_h, beta_h, thr_h,
        b_h2, beta_h2, thr_h2,
        W_out, b_out, beta_out,
        WhT, Wh2T, emb, rec, sG1, sG2);

    pred_kernel<<<BB / 256, 256, 0, stream>>>(rec, W_pred, b_pred, (float*)d_out);
}

// Round 12
// 3977.330 us; speedup vs baseline: 1.3269x; 1.3269x over previous
//
#include <hip/hip_runtime.h>
#include <hip/hip_bf16.h>

#define TT 64
#define BB 4096
#define HH 256
#define BMb 16             // batches per block
#define NBLK (BB / BMb)    // 256 blocks -> 1 block/CU, 4 waves (1/SIMD)

typedef short bf16x8_t __attribute__((ext_vector_type(8)));
typedef float f32x4_t  __attribute__((ext_vector_type(4)));

// d_ws layout (byte offsets)
#define WS_WA_B   0u          // split bf16 weights: 2 layers*3 parts*8kt*16nt*64lane*8j shorts = 768 KB
#define WS_EMB_B  786432u     // emb f32
#define WS_REC_B  1048576u    // rec f32 [T][B][4], 4 MB

__device__ __forceinline__ float clip01f(float v) {
    return fminf(fmaxf(v, 0.0f), 1.0f);
}

__global__ __launch_bounds__(64) void setup_emb_kernel(float* __restrict__ emb) {
    int i = threadIdx.x;
    const double sigma = 64.0 / 10.0;
    const double c = 32.0;
    double d = ((double)i - c) / sigma;
    double e = exp(-0.5 * (d * d));
    double d0 = (0.0 - c) / sigma;
    double emin = exp(-0.5 * (d0 * d0));
    emb[i] = (float)((e - emin) / (1.0 - emin));
}

// Exact 3-way split w = hi + mid + lo into bf16 parts (Sterbenz-exact residuals;
// bf16 exponent range == f32, residual after two 8-bit captures has <=8 sig bits).
// Output pre-swizzled to A-fragment order for mfma_f32_16x16x32_bf16:
// A[m=lane&15][k=(lane>>4)*8+j], flat = ((((layer*3+part)*8+kt)*16+ntile)*64+lane)*8+j
__global__ __launch_bounds__(256) void split_weights_kernel(
    const float* __restrict__ W_h, const float* __restrict__ W_h2,
    unsigned short* __restrict__ WA)
{
    int flat = blockIdx.x * 256 + threadIdx.x;     // < 393216
    int j     = flat & 7;
    int lane  = (flat >> 3) & 63;
    int ntile = (flat >> 9) & 15;
    int kt    = (flat >> 13) & 7;
    int rest  = flat >> 16;                        // 0..5
    int part  = rest % 3;
    int layer = rest / 3;
    int k = kt * 32 + (lane >> 4) * 8 + j;
    int n = ntile * 16 + (lane & 15);
    const float* W = layer ? W_h2 : W_h;           // row-major [n][k] = W[n*256+k]
    float w = W[n * HH + k];
    __hip_bfloat16 h = __float2bfloat16(w);
    float r1 = w - __bfloat162float(h);
    __hip_bfloat16 m = __float2bfloat16(r1);
    float r2 = r1 - __bfloat162float(m);
    __hip_bfloat16 l = __float2bfloat16(r2);
    __hip_bfloat16 v = (part == 0) ? h : ((part == 1) ? m : l);
    WA[flat] = *reinterpret_cast<unsigned short*>(&v);
}

union U16x8 { uint4 u; bf16x8_t v; };

// D[tile] += sum_k A(weights)*B(spikes): kt-major, 3 parts, 4 n-tiles per wave.
__device__ __forceinline__ void mfma_layer(const unsigned short* __restrict__ WA, int layer,
                                           const unsigned short* __restrict__ sbuf,
                                           int w, int lane, f32x4_t D[4])
{
    const uint4* Wp = (const uint4*)WA;
    const uint4* Bp = (const uint4*)sbuf;
#pragma unroll
    for (int kt = 0; kt < 8; ++kt) {
        U16x8 braw; braw.u = Bp[kt * 64 + lane];   // ds_read_b128, B-frag (spikes)
#pragma unroll
        for (int part = 0; part < 3; ++part) {
#pragma unroll
            for (int tile = 0; tile < 4; ++tile) {
                int idx = (((layer * 3 + part) * 8 + kt) * 16 + (w * 4 + tile)) * 64 + lane;
                U16x8 araw; araw.u = Wp[idx];      // global b128, coalesced, L2-resident
                D[tile] = __builtin_amdgcn_mfma_f32_16x16x32_bf16(araw.v, braw.v, D[tile], 0, 0, 0);
            }
        }
    }
}

// Write one tile's 4 spike bf16 (regs 0..3) into B-fragment LDS layout.
// k = w*64 + tile*16 + g*4 + reg -> kt2 = w*2 + (tile>>1), q = ((tile&1)<<1)|(g>>1),
// j0 = (g&1)*4; dst lane = (q<<4)|b; 4 consecutive j -> one b64 write.
__device__ __forceinline__ void write_spike_tile(unsigned short* buf, int w, int tile,
                                                 int g, int b,
                                                 unsigned s0, unsigned s1v,
                                                 unsigned s2v, unsigned s3v)
{
    int kt2 = w * 2 + (tile >> 1);
    int q = ((tile & 1) << 1) | (g >> 1);
    int dst_lane = (q << 4) | b;
    unsigned lo = s0 | (s1v << 16);
    unsigned hi = s2v | (s3v << 16);
    uint2* p = (uint2*)(buf + ((kt2 * 64 + dst_lane) * 8 + (g & 1) * 4));
    *p = make_uint2(lo, hi);
}

__global__ __launch_bounds__(256, 1) void snn_main_kernel(
    const float* __restrict__ x,
    const float* __restrict__ W_in, const float* __restrict__ b_in,
    const float* __restrict__ beta_in, const float* __restrict__ thr_in,
    const float* __restrict__ b_h, const float* __restrict__ beta_h, const float* __restrict__ thr_h,
    const float* __restrict__ b_h2, const float* __restrict__ beta_h2, const float* __restrict__ thr_h2,
    const float* __restrict__ W_out, const float* __restrict__ b_out, const float* __restrict__ beta_out,
    const unsigned short* __restrict__ WA, const float* __restrict__ emb,
    float* __restrict__ rec)
{
#pragma clang fp contract(off)   // all contraction EXPLICIT via fmaf
    const int tid = threadIdx.x;
    const int w = tid >> 6;
    const int lane = tid & 63;
    const int b = lane & 15;      // batch column (D col = lane&15)
    const int g = lane >> 4;      // row group   (D row = g*4+reg)
    const int b0 = blockIdx.x * BMb;

    __shared__ unsigned short sbuf1[8 * 64 * 8];   // B-frags spikes layer1 (8 KB)
    __shared__ unsigned short sbuf2[8 * 64 * 8];   // B-frags spikes layer2 (8 KB)
    __shared__ unsigned long long M3L[4][4][4];    // [w][tile][reg] ballots of s3
    __shared__ float WoutS[2 * HH];

    WoutS[tid] = W_out[tid];
    WoutS[tid + 256] = W_out[tid + 256];

    // per-thread params for its 16 neurons: n = w*64 + tile*16 + g*4 + reg
    float wi0[16], wi1[16], wi2[16], biA[16], bt1A[16], th1A[16];
    float bhA[16], bt2A[16], th2A[16], bh2A[16], bt3A[16], th3A[16];
#pragma unroll
    for (int tile = 0; tile < 4; ++tile)
#pragma unroll
        for (int reg = 0; reg < 4; ++reg) {
            int i = tile * 4 + reg;
            int n = w * 64 + tile * 16 + g * 4 + reg;
            wi0[i] = W_in[n * 3]; wi1[i] = W_in[n * 3 + 1]; wi2[i] = W_in[n * 3 + 2];
            biA[i] = b_in[n];  bt1A[i] = clip01f(beta_in[n]);  th1A[i] = thr_in[n];
            bhA[i] = b_h[n];   bt2A[i] = clip01f(beta_h[n]);   th2A[i] = thr_h[n];
            bh2A[i] = b_h2[n]; bt3A[i] = clip01f(beta_h2[n]);  th3A[i] = thr_h2[n];
        }

    float m1[16], m2[16], m4[16];
#pragma unroll
    for (int i = 0; i < 16; ++i) { m1[i] = 0.f; m2[i] = 0.f; m4[i] = 0.f; }

    // li_out walker state (wave 0, lanes 0..31): wb = batch, ooc = channel
    const int wb = lane & 15;
    const int ooc = (lane >> 4) & 1;
    float bto = clip01f(beta_out[ooc]);
    float bo = b_out[ooc];
    float m3s = 0.f;

    for (int t = 0; t < TT; ++t) {
        float et = emb[t];
        const float* xp = x + ((size_t)t * BB + b0 + b) * 3;
        float x0 = xp[0], x1 = xp[1], x2 = xp[2];
        float xe0 = x0 * et, xe1 = x1 * et, xe2 = x2 * et;   // rounded first (array op)

        // ---- layer 1: exact f32 chain + contracted LIF; spikes -> B-frag LDS ----
        {
            unsigned sp[16];
#pragma unroll
            for (int i = 0; i < 16; ++i) {
                float a1 = xe0 * wi0[i];
                a1 = fmaf(xe1, wi1[i], a1);
                a1 = fmaf(xe2, wi2[i], a1);
                float cur = a1 + biA[i];
                float rf = ((m1[i] - th1A[i]) > 0.f) ? 1.f : 0.f;
                float mm = fmaf(bt1A[i], m1[i], cur);
                mm = fmaf(-rf, th1A[i], mm);
                m1[i] = mm;
                sp[i] = ((mm - th1A[i]) > 0.f) ? 0x3F80u : 0u;   // bf16 1.0 / 0.0
            }
#pragma unroll
            for (int tile = 0; tile < 4; ++tile)
                write_spike_tile(sbuf1, w, tile, g, b,
                                 sp[tile * 4], sp[tile * 4 + 1], sp[tile * 4 + 2], sp[tile * 4 + 3]);
        }
        __syncthreads();

        // ---- layer 2: MFMA (3-part exact bf16 split), epilogue LIF ----
        {
            f32x4_t D[4];
#pragma unroll
            for (int tile = 0; tile < 4; ++tile) D[tile] = (f32x4_t){0.f, 0.f, 0.f, 0.f};
            mfma_layer(WA, 0, sbuf1, w, lane, D);
            unsigned sp[16];
#pragma unroll
            for (int tile = 0; tile < 4; ++tile)
#pragma unroll
                for (int reg = 0; reg < 4; ++reg) {
                    int i = tile * 4 + reg;
                    float cur = D[tile][reg] + bhA[i];
                    float rf = ((m2[i] - th2A[i]) > 0.f) ? 1.f : 0.f;
                    float mm = fmaf(bt2A[i], m2[i], cur);
                    mm = fmaf(-rf, th2A[i], mm);
                    m2[i] = mm;
                    sp[i] = ((mm - th2A[i]) > 0.f) ? 0x3F80u : 0u;
                }
#pragma unroll
            for (int tile = 0; tile < 4; ++tile)
                write_spike_tile(sbuf2, w, tile, g, b,
                                 sp[tile * 4], sp[tile * 4 + 1], sp[tile * 4 + 2], sp[tile * 4 + 3]);
        }
        __syncthreads();

        // ---- layer 3: MFMA, epilogue LIF -> ballots for li_out ----
        {
            f32x4_t D[4];
#pragma unroll
            for (int tile = 0; tile < 4; ++tile) D[tile] = (f32x4_t){0.f, 0.f, 0.f, 0.f};
            mfma_layer(WA, 1, sbuf2, w, lane, D);
#pragma unroll
            for (int tile = 0; tile < 4; ++tile)
#pragma unroll
                for (int reg = 0; reg < 4; ++reg) {
                    int i = tile * 4 + reg;
                    float cur = D[tile][reg] + bh2A[i];
                    float rf = ((m4[i] - th3A[i]) > 0.f) ? 1.f : 0.f;
                    float mm = fmaf(bt3A[i], m4[i], cur);
                    mm = fmaf(-rf, th3A[i], mm);
                    m4[i] = mm;
                    bool s3 = (mm - th3A[i]) > 0.f;
                    unsigned long long mk = __ballot(s3);   // bit at lane = (g<<4)|b
                    if (lane == 0) M3L[w][tile][reg] = mk;
                }
        }
        __syncthreads();

        // ---- li_out (R8-exact): sequential k=0..255 chain; contracted m3 update ----
        if (w == 0 && lane < 32) {
            float p = 0.f;
            for (int k = 0; k < HH; ++k) {
                int ww = k >> 6, tile = (k >> 4) & 3, gg = (k >> 2) & 3, reg = k & 3;
                unsigned long long word = M3L[ww][tile][reg];
                unsigned w32 = (gg < 2) ? (unsigned)word : (unsigned)(word >> 32);
                int sh = ((gg & 1) << 4) | wb;
                unsigned bit = (w32 >> sh) & 1u;
                float wv = WoutS[ooc * HH + k];
                p = p + (bit ? wv : 0.f);           // skip-zero == exact chain
            }
            float mm3 = fmaf(bto, m3s, p);
            mm3 = mm3 + bo;
            m3s = mm3;
            float spk = ((m3s - 1.0f) > 0.f) ? 1.f : 0.f;
            float om3 = __shfl_xor(m3s, 16, 64);
            float osp = __shfl_xor(spk, 16, 64);
            if (lane < 16) {
                *(float4*)(rec + ((size_t)t * BB + b0 + wb) * 4) =
                    make_float4(spk, osp, m3s, om3);
            }
        }
        // M3L rewritten only before next BAR3; wave0 passes next BAR1/2 after walker.
    }
}

// out[r,o] = (ascending-k fma dot) + b_pred[o]
__global__ __launch_bounds__(256) void pred_kernel(
    const float* __restrict__ rec, const float* __restrict__ W_pred,
    const float* __restrict__ b_pred, float* __restrict__ out)
{
#pragma clang fp contract(off)
    int r = blockIdx.x * 256 + threadIdx.x;   // 0..4095
    const float* f = rec + (size_t)r * 256;
    float a0 = 0.f, a1 = 0.f;
#pragma unroll 4
    for (int c = 0; c < 256; ++c) {
        float v = f[c];
        a0 = fmaf(v, W_pred[c], a0);
        a1 = fmaf(v, W_pred[256 + c], a1);
    }
    out[r * 2 + 0] = a0 + b_pred[0];
    out[r * 2 + 1] = a1 + b_pred[1];
}

extern "C" void kernel_launch(void* const* d_in, const int* in_sizes, int n_in,
                              void* d_out, int out_size, void* d_ws, size_t ws_size,
                              hipStream_t stream)
{
    const float* x        = (const float*)d_in[0];
    const float* W_in     = (const float*)d_in[1];
    const float* b_in     = (const float*)d_in[2];
    const float* beta_in  = (const float*)d_in[3];
    const float* thr_in   = (const float*)d_in[4];
    const float* W_h      = (const float*)d_in[5];
    const float* b_h      = (const float*)d_in[6];
    const float* beta_h   = (const float*)d_in[7];
    const float* thr_h    = (const float*)d_in[8];
    const float* W_h2     = (const float*)d_in[9];
    const float* b_h2     = (const float*)d_in[10];
    const float* beta_h2  = (const float*)d_in[11];
    const float* thr_h2   = (const float*)d_in[12];
    const float* W_out    = (const float*)d_in[13];
    const float* b_out    = (const float*)d_in[14];
    const float* beta_out = (const float*)d_in[15];
    const float* W_pred   = (const float*)d_in[16];
    const float* b_pred   = (const float*)d_in[17];

    char* ws = (char*)d_ws;
    unsigned short* WA = (unsigned short*)(ws + WS_WA_B);
    float* emb = (float*)(ws + WS_EMB_B);
    float* rec = (float*)(ws + WS_REC_B);

    split_weights_kernel<<<1536, 256, 0, stream>>>(W_h, W_h2, WA);
    setup_emb_kernel<<<1, 64, 0, stream>>>(emb);

    snn_main_kernel<<<NBLK, 256, 0, stream>>>(
        x, W_in, b_in, beta_in, thr_in,
        b_h, beta_h, thr_h,
        b_h2, beta_h2, thr_h2,
        W_out, b_out, beta_out,
        WA, emb, rec);

    pred_kernel<<<BB / 256, 256, 0, stream>>>(rec, W_pred, b_pred, (float*)d_out);
}

// Round 13
// 2923.999 us; speedup vs baseline: 1.8049x; 1.3602x over previous
//
#include <hip/hip_runtime.h>
#include <hip/hip_bf16.h>

#define TT 64
#define BB 4096
#define HH 256
#define BMb 16             // batches per block
#define NBLK (BB / BMb)    // 256 blocks -> 1 block/CU, 4 waves (1/SIMD)

typedef short bf16x8_t __attribute__((ext_vector_type(8)));
typedef float f32x4_t  __attribute__((ext_vector_type(4)));

// d_ws layout (byte offsets)
#define WS_WA_B   0u          // split bf16 weights: 2 layers*3 parts*8kt*16nt*64lane*8j shorts = 768 KB
#define WS_EMB_B  786432u     // emb f32
#define WS_REC_B  1048576u    // rec f32 [T][B][4], 4 MB

__device__ __forceinline__ float clip01f(float v) {
    return fminf(fmaxf(v, 0.0f), 1.0f);
}

__global__ __launch_bounds__(64) void setup_emb_kernel(float* __restrict__ emb) {
    int i = threadIdx.x;
    const double sigma = 64.0 / 10.0;
    const double c = 32.0;
    double d = ((double)i - c) / sigma;
    double e = exp(-0.5 * (d * d));
    double d0 = (0.0 - c) / sigma;
    double emin = exp(-0.5 * (d0 * d0));
    emb[i] = (float)((e - emin) / (1.0 - emin));
}

// Exact 3-way split w = hi + mid + lo into bf16 parts (residuals exact).
// Pre-swizzled to A-fragment order for mfma_f32_16x16x32_bf16:
// A[m=lane&15][k=(lane>>4)*8+j], flat = ((((layer*3+part)*8+kt)*16+ntile)*64+lane)*8+j
__global__ __launch_bounds__(256) void split_weights_kernel(
    const float* __restrict__ W_h, const float* __restrict__ W_h2,
    unsigned short* __restrict__ WA)
{
    int flat = blockIdx.x * 256 + threadIdx.x;     // < 393216
    int j     = flat & 7;
    int lane  = (flat >> 3) & 63;
    int ntile = (flat >> 9) & 15;
    int kt    = (flat >> 13) & 7;
    int rest  = flat >> 16;                        // 0..5
    int part  = rest % 3;
    int layer = rest / 3;
    int k = kt * 32 + (lane >> 4) * 8 + j;
    int n = ntile * 16 + (lane & 15);
    const float* W = layer ? W_h2 : W_h;           // row-major [n][k] = W[n*256+k]
    float w = W[n * HH + k];
    __hip_bfloat16 h = __float2bfloat16(w);
    float r1 = w - __bfloat162float(h);
    __hip_bfloat16 m = __float2bfloat16(r1);
    float r2 = r1 - __bfloat162float(m);
    __hip_bfloat16 l = __float2bfloat16(r2);
    __hip_bfloat16 v = (part == 0) ? h : ((part == 1) ? m : l);
    WA[flat] = *reinterpret_cast<unsigned short*>(&v);
}

union U16x8 { uint4 u; bf16x8_t v; };

// D[tile] += sum_k A(weights)*B(spikes): kt-major, 3 parts, 4 n-tiles per wave.
__device__ __forceinline__ void mfma_layer(const unsigned short* __restrict__ WA, int layer,
                                           const unsigned short* __restrict__ sbuf,
                                           int w, int lane, f32x4_t D[4])
{
    const uint4* Wp = (const uint4*)WA;
    const uint4* Bp = (const uint4*)sbuf;
#pragma unroll
    for (int kt = 0; kt < 8; ++kt) {
        U16x8 braw; braw.u = Bp[kt * 64 + lane];   // ds_read_b128, B-frag (spikes)
#pragma unroll
        for (int part = 0; part < 3; ++part) {
#pragma unroll
            for (int tile = 0; tile < 4; ++tile) {
                int idx = (((layer * 3 + part) * 8 + kt) * 16 + (w * 4 + tile)) * 64 + lane;
                U16x8 araw; araw.u = Wp[idx];      // global b128, coalesced, L2-resident
                D[tile] = __builtin_amdgcn_mfma_f32_16x16x32_bf16(araw.v, braw.v, D[tile], 0, 0, 0);
            }
        }
    }
}

// Write one tile's 4 spike bf16 (regs 0..3) into B-fragment LDS layout.
__device__ __forceinline__ void write_spike_tile(unsigned short* buf, int w, int tile,
                                                 int g, int b,
                                                 unsigned s0, unsigned s1v,
                                                 unsigned s2v, unsigned s3v)
{
    int kt2 = w * 2 + (tile >> 1);
    int q = ((tile & 1) << 1) | (g >> 1);
    int dst_lane = (q << 4) | b;
    unsigned lo = s0 | (s1v << 16);
    unsigned hi = s2v | (s3v << 16);
    uint2* p = (uint2*)(buf + ((kt2 * 64 + dst_lane) * 8 + (g & 1) * 4));
    *p = make_uint2(lo, hi);
}

__global__ __launch_bounds__(256, 1) void snn_main_kernel(
    const float* __restrict__ x,
    const float* __restrict__ W_in, const float* __restrict__ b_in,
    const float* __restrict__ beta_in, const float* __restrict__ thr_in,
    const float* __restrict__ b_h, const float* __restrict__ beta_h, const float* __restrict__ thr_h,
    const float* __restrict__ b_h2, const float* __restrict__ beta_h2, const float* __restrict__ thr_h2,
    const float* __restrict__ W_out, const float* __restrict__ b_out, const float* __restrict__ beta_out,
    const unsigned short* __restrict__ WA, const float* __restrict__ emb,
    float* __restrict__ rec)
{
#pragma clang fp contract(off)   // all contraction EXPLICIT via fmaf
    const int tid = threadIdx.x;
    const int w = tid >> 6;
    const int lane = tid & 63;
    const int b = lane & 15;      // batch column (D col = lane&15)
    const int g = lane >> 4;      // row group   (D row = g*4+reg)
    const int b0 = blockIdx.x * BMb;

    __shared__ unsigned short sbuf1[8 * 64 * 8];   // B-frags spikes layer1 (8 KB)
    __shared__ unsigned short sbuf2[8 * 64 * 8];   // B-frags spikes layer2 (8 KB)
    __shared__ unsigned long long M3L[4][4][4];    // [w][tile][reg] ballots of s3
    __shared__ float WoutS[2 * HH];
    // Param tables in LDS (beta pre-clipped). No per-thread param arrays -> no spills.
    __shared__ float4 PL1a[HH];   // {wi0, wi1, wi2, b_in}
    __shared__ float4 PL1b[HH];   // {bt1c, th1, -, -}
    __shared__ float4 PL2[HH];    // {b_h,  bt2c, th2, -}
    __shared__ float4 PL3[HH];    // {b_h2, bt3c, th3, -}

    WoutS[tid] = W_out[tid];
    WoutS[tid + 256] = W_out[tid + 256];
    {
        int n = tid;
        PL1a[n] = make_float4(W_in[n * 3], W_in[n * 3 + 1], W_in[n * 3 + 2], b_in[n]);
        PL1b[n] = make_float4(clip01f(beta_in[n]), thr_in[n], 0.f, 0.f);
        PL2[n]  = make_float4(b_h[n],  clip01f(beta_h[n]),  thr_h[n],  0.f);
        PL3[n]  = make_float4(b_h2[n], clip01f(beta_h2[n]), thr_h2[n], 0.f);
    }
    __syncthreads();

    float m1[16], m2[16], m4[16];
#pragma unroll
    for (int i = 0; i < 16; ++i) { m1[i] = 0.f; m2[i] = 0.f; m4[i] = 0.f; }

    // li_out walker state (wave 0, lanes 0..31): wb = batch, ooc = channel
    const int wb = lane & 15;
    const int ooc = (lane >> 4) & 1;
    float bto = clip01f(beta_out[ooc]);
    float bo = b_out[ooc];
    float m3s = 0.f;

    const int nbase = w * 64 + g * 4;   // n = nbase + tile*16 + reg

    for (int t = 0; t < TT; ++t) {
        float et = emb[t];
        const float* xp = x + ((size_t)t * BB + b0 + b) * 3;
        float x0 = xp[0], x1 = xp[1], x2 = xp[2];
        float xe0 = x0 * et, xe1 = x1 * et, xe2 = x2 * et;   // rounded first (array op)

        // ---- layer 1: exact f32 chain + contracted LIF; spikes -> B-frag LDS ----
        {
            unsigned sp[16];
#pragma unroll
            for (int tile = 0; tile < 4; ++tile)
#pragma unroll
                for (int reg = 0; reg < 4; ++reg) {
                    int i = tile * 4 + reg;
                    int n = nbase + tile * 16 + reg;
                    float4 pa = PL1a[n];
                    float4 pb = PL1b[n];
                    float a1 = xe0 * pa.x;
                    a1 = fmaf(xe1, pa.y, a1);
                    a1 = fmaf(xe2, pa.z, a1);
                    float cur = a1 + pa.w;
                    float rf = ((m1[i] - pb.y) > 0.f) ? 1.f : 0.f;
                    float mm = fmaf(pb.x, m1[i], cur);
                    mm = fmaf(-rf, pb.y, mm);
                    m1[i] = mm;
                    sp[i] = ((mm - pb.y) > 0.f) ? 0x3F80u : 0u;   // bf16 1.0 / 0.0
                }
#pragma unroll
            for (int tile = 0; tile < 4; ++tile)
                write_spike_tile(sbuf1, w, tile, g, b,
                                 sp[tile * 4], sp[tile * 4 + 1], sp[tile * 4 + 2], sp[tile * 4 + 3]);
        }
        __syncthreads();

        // ---- layer 2: MFMA (3-part exact bf16 split), epilogue LIF ----
        {
            f32x4_t D[4];
#pragma unroll
            for (int tile = 0; tile < 4; ++tile) D[tile] = (f32x4_t){0.f, 0.f, 0.f, 0.f};
            mfma_layer(WA, 0, sbuf1, w, lane, D);
            unsigned sp[16];
#pragma unroll
            for (int tile = 0; tile < 4; ++tile)
#pragma unroll
                for (int reg = 0; reg < 4; ++reg) {
                    int i = tile * 4 + reg;
                    int n = nbase + tile * 16 + reg;
                    float4 p2 = PL2[n];
                    float cur = D[tile][reg] + p2.x;
                    float rf = ((m2[i] - p2.z) > 0.f) ? 1.f : 0.f;
                    float mm = fmaf(p2.y, m2[i], cur);
                    mm = fmaf(-rf, p2.z, mm);
                    m2[i] = mm;
                    sp[i] = ((mm - p2.z) > 0.f) ? 0x3F80u : 0u;
                }
#pragma unroll
            for (int tile = 0; tile < 4; ++tile)
                write_spike_tile(sbuf2, w, tile, g, b,
                                 sp[tile * 4], sp[tile * 4 + 1], sp[tile * 4 + 2], sp[tile * 4 + 3]);
        }
        __syncthreads();

        // ---- layer 3: MFMA, epilogue LIF -> ballots for li_out ----
        {
            f32x4_t D[4];
#pragma unroll
            for (int tile = 0; tile < 4; ++tile) D[tile] = (f32x4_t){0.f, 0.f, 0.f, 0.f};
            mfma_layer(WA, 1, sbuf2, w, lane, D);
#pragma unroll
            for (int tile = 0; tile < 4; ++tile)
#pragma unroll
                for (int reg = 0; reg < 4; ++reg) {
                    int i = tile * 4 + reg;
                    int n = nbase + tile * 16 + reg;
                    float4 p3 = PL3[n];
                    float cur = D[tile][reg] + p3.x;
                    float rf = ((m4[i] - p3.z) > 0.f) ? 1.f : 0.f;
                    float mm = fmaf(p3.y, m4[i], cur);
                    mm = fmaf(-rf, p3.z, mm);
                    m4[i] = mm;
                    bool s3 = (mm - p3.z) > 0.f;
                    unsigned long long mk = __ballot(s3);   // bit at lane = (g<<4)|b
                    if (lane == 0) M3L[w][tile][reg] = mk;
                }
        }
        __syncthreads();

        // ---- li_out (R8-exact): sequential k=0..255 chain; contracted m3 update ----
        if (w == 0 && lane < 32) {
            float p = 0.f;
            for (int k = 0; k < HH; ++k) {
                int ww = k >> 6, tile = (k >> 4) & 3, gg = (k >> 2) & 3, reg = k & 3;
                unsigned long long word = M3L[ww][tile][reg];
                unsigned w32 = (gg < 2) ? (unsigned)word : (unsigned)(word >> 32);
                int sh = ((gg & 1) << 4) | wb;
                unsigned bit = (w32 >> sh) & 1u;
                float wv = WoutS[ooc * HH + k];
                p = p + (bit ? wv : 0.f);           // skip-zero == exact chain
            }
            float mm3 = fmaf(bto, m3s, p);
            mm3 = mm3 + bo;
            m3s = mm3;
            float spk = ((m3s - 1.0f) > 0.f) ? 1.f : 0.f;
            float om3 = __shfl_xor(m3s, 16, 64);
            float osp = __shfl_xor(spk, 16, 64);
            if (lane < 16) {
                *(float4*)(rec + ((size_t)t * BB + b0 + wb) * 4) =
                    make_float4(spk, osp, m3s, om3);
            }
        }
        // M3L rewritten only before next BAR3; wave0 passes next BAR1/2 after walker.
    }
}

// out[r,o] = (ascending-k fma dot) + b_pred[o]
__global__ __launch_bounds__(256) void pred_kernel(
    const float* __restrict__ rec, const float* __restrict__ W_pred,
    const float* __restrict__ b_pred, float* __restrict__ out)
{
#pragma clang fp contract(off)
    int r = blockIdx.x * 256 + threadIdx.x;   // 0..4095
    const float* f = rec + (size_t)r * 256;
    float a0 = 0.f, a1 = 0.f;
#pragma unroll 4
    for (int c = 0; c < 256; ++c) {
        float v = f[c];
        a0 = fmaf(v, W_pred[c], a0);
        a1 = fmaf(v, W_pred[256 + c], a1);
    }
    out[r * 2 + 0] = a0 + b_pred[0];
    out[r * 2 + 1] = a1 + b_pred[1];
}

extern "C" void kernel_launch(void* const* d_in, const int* in_sizes, int n_in,
                              void* d_out, int out_size, void* d_ws, size_t ws_size,
                              hipStream_t stream)
{
    const float* x        = (const float*)d_in[0];
    const float* W_in     = (const float*)d_in[1];
    const float* b_in     = (const float*)d_in[2];
    const float* beta_in  = (const float*)d_in[3];
    const float* thr_in   = (const float*)d_in[4];
    const float* W_h      = (const float*)d_in[5];
    const float* b_h      = (const float*)d_in[6];
    const float* beta_h   = (const float*)d_in[7];
    const float* thr_h    = (const float*)d_in[8];
    const float* W_h2     = (const float*)d_in[9];
    const float* b_h2     = (const float*)d_in[10];
    const float* beta_h2  = (const float*)d_in[11];
    const float* thr_h2   = (const float*)d_in[12];
    const float* W_out    = (const float*)d_in[13];
    const float* b_out    = (const float*)d_in[14];
    const float* beta_out = (const float*)d_in[15];
    const float* W_pred   = (const float*)d_in[16];
    const float* b_pred   = (const float*)d_in[17];

    char* ws = (char*)d_ws;
    unsigned short* WA = (unsigned short*)(ws + WS_WA_B);
    float* emb = (float*)(ws + WS_EMB_B);
    float* rec = (float*)(ws + WS_REC_B);

    split_weights_kernel<<<1536, 256, 0, stream>>>(W_h, W_h2, WA);
    setup_emb_kernel<<<1, 64, 0, stream>>>(emb);

    snn_main_kernel<<<NBLK, 256, 0, stream>>>(
        x, W_in, b_in, beta_in, thr_in,
        b_h, beta_h, thr_h,
        b_h2, beta_h2, thr_h2,
        W_out, b_out, beta_out,
        WA, emb, rec);

    pred_kernel<<<BB / 256, 256, 0, stream>>>(rec, W_pred, b_pred, (float*)d_out);
}

// Round 14
// 1364.275 us; speedup vs baseline: 3.8684x; 2.1433x over previous
//
#include <hip/hip_runtime.h>
#include <hip/hip_bf16.h>

#define TT 64
#define BB 4096
#define HH 256
#define BMb 16             // batches per block
#define NBLK (BB / BMb)    // 256 blocks -> 1 block/CU, 4 waves (1/SIMD)

typedef short bf16x8_t __attribute__((ext_vector_type(8)));
typedef float f32x4_t  __attribute__((ext_vector_type(4)));

// d_ws layout (byte offsets)
#define WS_WA_B   0u          // split bf16 weights: 2 layers*3 parts*8kt*16nt*64lane*8j shorts = 768 KB
#define WS_EMB_B  786432u     // emb f32
#define WS_REC_B  1048576u    // rec f32 [T][B][4], 4 MB

__device__ __forceinline__ float clip01f(float v) {
    return fminf(fmaxf(v, 0.0f), 1.0f);
}

__global__ __launch_bounds__(64) void setup_emb_kernel(float* __restrict__ emb) {
    int i = threadIdx.x;
    const double sigma = 64.0 / 10.0;
    const double c = 32.0;
    double d = ((double)i - c) / sigma;
    double e = exp(-0.5 * (d * d));
    double d0 = (0.0 - c) / sigma;
    double emin = exp(-0.5 * (d0 * d0));
    emb[i] = (float)((e - emin) / (1.0 - emin));
}

// Exact 3-way split w = hi + mid + lo into bf16 parts (residuals exact).
// Pre-swizzled to A-fragment order for mfma_f32_16x16x32_bf16:
// A[m=lane&15][k=(lane>>4)*8+j], flat = ((((layer*3+part)*8+kt)*16+ntile)*64+lane)*8+j
__global__ __launch_bounds__(256) void split_weights_kernel(
    const float* __restrict__ W_h, const float* __restrict__ W_h2,
    unsigned short* __restrict__ WA)
{
    int flat = blockIdx.x * 256 + threadIdx.x;     // < 393216
    int j     = flat & 7;
    int lane  = (flat >> 3) & 63;
    int ntile = (flat >> 9) & 15;
    int kt    = (flat >> 13) & 7;
    int rest  = flat >> 16;                        // 0..5
    int part  = rest % 3;
    int layer = rest / 3;
    int k = kt * 32 + (lane >> 4) * 8 + j;
    int n = ntile * 16 + (lane & 15);
    const float* W = layer ? W_h2 : W_h;           // row-major [n][k] = W[n*256+k]
    float w = W[n * HH + k];
    __hip_bfloat16 h = __float2bfloat16(w);
    float r1 = w - __bfloat162float(h);
    __hip_bfloat16 m = __float2bfloat16(r1);
    float r2 = r1 - __bfloat162float(m);
    __hip_bfloat16 l = __float2bfloat16(r2);
    __hip_bfloat16 v = (part == 0) ? h : ((part == 1) ? m : l);
    WA[flat] = *reinterpret_cast<unsigned short*>(&v);
}

union U16x8 { uint4 u; bf16x8_t v; };

// D[tile] += sum_k A(weights)*B(spikes).
// kt loop NOT unrolled (unroll 1): kt stays a loop variable, so the 12 A-fragment
// loads per iteration can't be hoisted/spilled across the t-loop (R13's 3.4 GB
// scratch bug). MFMA issue order kt -> part -> tile is IDENTICAL to R12/R13 ->
// bit-identical D accumulation.
__device__ __forceinline__ void mfma_layer(const unsigned short* __restrict__ WA, int layer,
                                           const unsigned short* __restrict__ sbuf,
                                           int w, int lane, f32x4_t D[4])
{
    const uint4* Wp = (const uint4*)WA + (size_t)layer * 3 * 8 * 16 * 64;
    const uint4* Bp = (const uint4*)sbuf;
#pragma unroll 1
    for (int kt = 0; kt < 8; ++kt) {
        U16x8 braw; braw.u = Bp[kt * 64 + lane];   // ds_read_b128, B-frag (spikes)
        uint4 a[12];                               // 12 loads in flight (48 VGPRs)
#pragma unroll
        for (int part = 0; part < 3; ++part)
#pragma unroll
            for (int tile = 0; tile < 4; ++tile)
                a[part * 4 + tile] = Wp[((part * 8 + kt) * 16 + (w * 4 + tile)) * 64 + lane];
#pragma unroll
        for (int part = 0; part < 3; ++part)
#pragma unroll
            for (int tile = 0; tile < 4; ++tile) {
                U16x8 ar; ar.u = a[part * 4 + tile];
                D[tile] = __builtin_amdgcn_mfma_f32_16x16x32_bf16(ar.v, braw.v, D[tile], 0, 0, 0);
            }
    }
}

// Write one tile's 4 spike bf16 (regs 0..3) into B-fragment LDS layout.
__device__ __forceinline__ void write_spike_tile(unsigned short* buf, int w, int tile,
                                                 int g, int b,
                                                 unsigned s0, unsigned s1v,
                                                 unsigned s2v, unsigned s3v)
{
    int kt2 = w * 2 + (tile >> 1);
    int q = ((tile & 1) << 1) | (g >> 1);
    int dst_lane = (q << 4) | b;
    unsigned lo = s0 | (s1v << 16);
    unsigned hi = s2v | (s3v << 16);
    uint2* p = (uint2*)(buf + ((kt2 * 64 + dst_lane) * 8 + (g & 1) * 4));
    *p = make_uint2(lo, hi);
}

__global__ __launch_bounds__(256, 1) void snn_main_kernel(
    const float* __restrict__ x,
    const float* __restrict__ W_in, const float* __restrict__ b_in,
    const float* __restrict__ beta_in, const float* __restrict__ thr_in,
    const float* __restrict__ b_h, const float* __restrict__ beta_h, const float* __restrict__ thr_h,
    const float* __restrict__ b_h2, const float* __restrict__ beta_h2, const float* __restrict__ thr_h2,
    const float* __restrict__ W_out, const float* __restrict__ b_out, const float* __restrict__ beta_out,
    const unsigned short* __restrict__ WA, const float* __restrict__ emb,
    float* __restrict__ rec)
{
#pragma clang fp contract(off)   // all contraction EXPLICIT via fmaf
    const int tid = threadIdx.x;
    const int w = tid >> 6;
    const int lane = tid & 63;
    const int b = lane & 15;      // batch column (D col = lane&15)
    const int g = lane >> 4;      // row group   (D row = g*4+reg)
    const int b0 = blockIdx.x * BMb;

    __shared__ unsigned short sbuf1[8 * 64 * 8];   // B-frags spikes layer1 (8 KB)
    __shared__ unsigned short sbuf2[8 * 64 * 8];   // B-frags spikes layer2 (8 KB)
    __shared__ unsigned long long M3L[4][4][4];    // [w][tile][reg] ballots of s3
    __shared__ float WoutS[2 * HH];
    // Param tables in LDS (beta pre-clipped) -> no per-thread param arrays.
    __shared__ float4 PL1a[HH];   // {wi0, wi1, wi2, b_in}
    __shared__ float4 PL1b[HH];   // {bt1c, th1, -, -}
    __shared__ float4 PL2[HH];    // {b_h,  bt2c, th2, -}
    __shared__ float4 PL3[HH];    // {b_h2, bt3c, th3, -}

    WoutS[tid] = W_out[tid];
    WoutS[tid + 256] = W_out[tid + 256];
    {
        int n = tid;
        PL1a[n] = make_float4(W_in[n * 3], W_in[n * 3 + 1], W_in[n * 3 + 2], b_in[n]);
        PL1b[n] = make_float4(clip01f(beta_in[n]), thr_in[n], 0.f, 0.f);
        PL2[n]  = make_float4(b_h[n],  clip01f(beta_h[n]),  thr_h[n],  0.f);
        PL3[n]  = make_float4(b_h2[n], clip01f(beta_h2[n]), thr_h2[n], 0.f);
    }
    __syncthreads();

    float m1[16], m2[16], m4[16];
#pragma unroll
    for (int i = 0; i < 16; ++i) { m1[i] = 0.f; m2[i] = 0.f; m4[i] = 0.f; }

    // li_out walker state (wave 0, lanes 0..31): wb = batch, ooc = channel
    const int wb = lane & 15;
    const int ooc = (lane >> 4) & 1;
    float bto = clip01f(beta_out[ooc]);
    float bo = b_out[ooc];
    float m3s = 0.f;

    const int nbase = w * 64 + g * 4;   // n = nbase + tile*16 + reg

    for (int t = 0; t < TT; ++t) {
        float et = emb[t];
        const float* xp = x + ((size_t)t * BB + b0 + b) * 3;
        float x0 = xp[0], x1 = xp[1], x2 = xp[2];
        float xe0 = x0 * et, xe1 = x1 * et, xe2 = x2 * et;   // rounded first (array op)

        // ---- layer 1: exact f32 chain + contracted LIF; spikes -> B-frag LDS ----
        {
            unsigned sp[16];
#pragma unroll
            for (int tile = 0; tile < 4; ++tile)
#pragma unroll
                for (int reg = 0; reg < 4; ++reg) {
                    int i = tile * 4 + reg;
                    int n = nbase + tile * 16 + reg;
                    float4 pa = PL1a[n];
                    float4 pb = PL1b[n];
                    float a1 = xe0 * pa.x;
                    a1 = fmaf(xe1, pa.y, a1);
                    a1 = fmaf(xe2, pa.z, a1);
                    float cur = a1 + pa.w;
                    float rf = ((m1[i] - pb.y) > 0.f) ? 1.f : 0.f;
                    float mm = fmaf(pb.x, m1[i], cur);
                    mm = fmaf(-rf, pb.y, mm);
                    m1[i] = mm;
                    sp[i] = ((mm - pb.y) > 0.f) ? 0x3F80u : 0u;   // bf16 1.0 / 0.0
                }
#pragma unroll
            for (int tile = 0; tile < 4; ++tile)
                write_spike_tile(sbuf1, w, tile, g, b,
                                 sp[tile * 4], sp[tile * 4 + 1], sp[tile * 4 + 2], sp[tile * 4 + 3]);
        }
        __syncthreads();

        // ---- layer 2: MFMA (3-part exact bf16 split), epilogue LIF ----
        {
            f32x4_t D[4];
#pragma unroll
            for (int tile = 0; tile < 4; ++tile) D[tile] = (f32x4_t){0.f, 0.f, 0.f, 0.f};
            mfma_layer(WA, 0, sbuf1, w, lane, D);
            unsigned sp[16];
#pragma unroll
            for (int tile = 0; tile < 4; ++tile)
#pragma unroll
                for (int reg = 0; reg < 4; ++reg) {
                    int i = tile * 4 + reg;
                    int n = nbase + tile * 16 + reg;
                    float4 p2 = PL2[n];
                    float cur = D[tile][reg] + p2.x;
                    float rf = ((m2[i] - p2.z) > 0.f) ? 1.f : 0.f;
                    float mm = fmaf(p2.y, m2[i], cur);
                    mm = fmaf(-rf, p2.z, mm);
                    m2[i] = mm;
                    sp[i] = ((mm - p2.z) > 0.f) ? 0x3F80u : 0u;
                }
#pragma unroll
            for (int tile = 0; tile < 4; ++tile)
                write_spike_tile(sbuf2, w, tile, g, b,
                                 sp[tile * 4], sp[tile * 4 + 1], sp[tile * 4 + 2], sp[tile * 4 + 3]);
        }
        __syncthreads();

        // ---- layer 3: MFMA, epilogue LIF -> ballots for li_out ----
        {
            f32x4_t D[4];
#pragma unroll
            for (int tile = 0; tile < 4; ++tile) D[tile] = (f32x4_t){0.f, 0.f, 0.f, 0.f};
            mfma_layer(WA, 1, sbuf2, w, lane, D);
#pragma unroll
            for (int tile = 0; tile < 4; ++tile)
#pragma unroll
                for (int reg = 0; reg < 4; ++reg) {
                    int i = tile * 4 + reg;
                    int n = nbase + tile * 16 + reg;
                    float4 p3 = PL3[n];
                    float cur = D[tile][reg] + p3.x;
                    float rf = ((m4[i] - p3.z) > 0.f) ? 1.f : 0.f;
                    float mm = fmaf(p3.y, m4[i], cur);
                    mm = fmaf(-rf, p3.z, mm);
                    m4[i] = mm;
                    bool s3 = (mm - p3.z) > 0.f;
                    unsigned long long mk = __ballot(s3);   // bit at lane = (g<<4)|b
                    if (lane == 0) M3L[w][tile][reg] = mk;
                }
        }
        __syncthreads();

        // ---- li_out (R8-exact): sequential k=0..255 chain; contracted m3 update ----
        if (w == 0 && lane < 32) {
            float p = 0.f;
            for (int k = 0; k < HH; ++k) {
                int ww = k >> 6, tile = (k >> 4) & 3, gg = (k >> 2) & 3, reg = k & 3;
                unsigned long long word = M3L[ww][tile][reg];
                unsigned w32 = (gg < 2) ? (unsigned)word : (unsigned)(word >> 32);
                int sh = ((gg & 1) << 4) | wb;
                unsigned bit = (w32 >> sh) & 1u;
                float wv = WoutS[ooc * HH + k];
                p = p + (bit ? wv : 0.f);           // skip-zero == exact chain
            }
            float mm3 = fmaf(bto, m3s, p);
            mm3 = mm3 + bo;
            m3s = mm3;
            float spk = ((m3s - 1.0f) > 0.f) ? 1.f : 0.f;
            float om3 = __shfl_xor(m3s, 16, 64);
            float osp = __shfl_xor(spk, 16, 64);
            if (lane < 16) {
                *(float4*)(rec + ((size_t)t * BB + b0 + wb) * 4) =
                    make_float4(spk, osp, m3s, om3);
            }
        }
        // M3L rewritten only before next BAR3; wave0 passes next BAR1/2 after walker.
    }
}

// out[r,o] = (ascending-k fma dot) + b_pred[o]
__global__ __launch_bounds__(256) void pred_kernel(
    const float* __restrict__ rec, const float* __restrict__ W_pred,
    const float* __restrict__ b_pred, float* __restrict__ out)
{
#pragma clang fp contract(off)
    int r = blockIdx.x * 256 + threadIdx.x;   // 0..4095
    const float* f = rec + (size_t)r * 256;
    float a0 = 0.f, a1 = 0.f;
#pragma unroll 4
    for (int c = 0; c < 256; ++c) {
        float v = f[c];
        a0 = fmaf(v, W_pred[c], a0);
        a1 = fmaf(v, W_pred[256 + c], a1);
    }
    out[r * 2 + 0] = a0 + b_pred[0];
    out[r * 2 + 1] = a1 + b_pred[1];
}

extern "C" void kernel_launch(void* const* d_in, const int* in_sizes, int n_in,
                              void* d_out, int out_size, void* d_ws, size_t ws_size,
                              hipStream_t stream)
{
    const float* x        = (const float*)d_in[0];
    const float* W_in     = (const float*)d_in[1];
    const float* b_in     = (const float*)d_in[2];
    const float* beta_in  = (const float*)d_in[3];
    const float* thr_in   = (const float*)d_in[4];
    const float* W_h      = (const float*)d_in[5];
    const float* b_h      = (const float*)d_in[6];
    const float* beta_h   = (const float*)d_in[7];
    const float* thr_h    = (const float*)d_in[8];
    const float* W_h2     = (const float*)d_in[9];
    const float* b_h2     = (const float*)d_in[10];
    const float* beta_h2  = (const float*)d_in[11];
    const float* thr_h2   = (const float*)d_in[12];
    const float* W_out    = (const float*)d_in[13];
    const float* b_out    = (const float*)d_in[14];
    const float* beta_out = (const float*)d_in[15];
    const float* W_pred   = (const float*)d_in[16];
    const float* b_pred   = (const float*)d_in[17];

    char* ws = (char*)d_ws;
    unsigned short* WA = (unsigned short*)(ws + WS_WA_B);
    float* emb = (float*)(ws + WS_EMB_B);
    float* rec = (float*)(ws + WS_REC_B);

    split_weights_kernel<<<1536, 256, 0, stream>>>(W_h, W_h2, WA);
    setup_emb_kernel<<<1, 64, 0, stream>>>(emb);

    snn_main_kernel<<<NBLK, 256, 0, stream>>>(
        x, W_in, b_in, beta_in, thr_in,
        b_h, beta_h, thr_h,
        b_h2, beta_h2, thr_h2,
        W_out, b_out, beta_out,
        WA, emb, rec);

    pred_kernel<<<BB / 256, 256, 0, stream>>>(rec, W_pred, b_pred, (float*)d_out);
}

// Round 15
// 1037.696 us; speedup vs baseline: 5.0859x; 1.3147x over previous
//
#include <hip/hip_runtime.h>
#include <hip/hip_bf16.h>

#define TT 64
#define BB 4096
#define HH 256
#define BMb 16             // batches per block
#define NBLK (BB / BMb)    // 256 blocks -> 1 block/CU, 16 waves (4/SIMD)

typedef short bf16x8_t __attribute__((ext_vector_type(8)));
typedef float f32x4_t  __attribute__((ext_vector_type(4)));

// d_ws layout (byte offsets)
#define WS_WA_B   0u          // split bf16 weights: 2 layers*3 parts*8kt*16nt*64lane*8j shorts = 768 KB
#define WS_EMB_B  786432u     // emb f32
#define WS_REC_B  1048576u    // rec f32 [T][B][4], 4 MB

__device__ __forceinline__ float clip01f(float v) {
    return fminf(fmaxf(v, 0.0f), 1.0f);
}

__global__ __launch_bounds__(64) void setup_emb_kernel(float* __restrict__ emb) {
    int i = threadIdx.x;
    const double sigma = 64.0 / 10.0;
    const double c = 32.0;
    double d = ((double)i - c) / sigma;
    double e = exp(-0.5 * (d * d));
    double d0 = (0.0 - c) / sigma;
    double emin = exp(-0.5 * (d0 * d0));
    emb[i] = (float)((e - emin) / (1.0 - emin));
}

// Exact 3-way split w = hi + mid + lo into bf16 parts (residuals exact).
// Pre-swizzled to A-fragment order for mfma_f32_16x16x32_bf16:
// A[m=lane&15][k=(lane>>4)*8+j], flat = ((((layer*3+part)*8+kt)*16+ntile)*64+lane)*8+j
__global__ __launch_bounds__(256) void split_weights_kernel(
    const float* __restrict__ W_h, const float* __restrict__ W_h2,
    unsigned short* __restrict__ WA)
{
    int flat = blockIdx.x * 256 + threadIdx.x;     // < 393216
    int j     = flat & 7;
    int lane  = (flat >> 3) & 63;
    int ntile = (flat >> 9) & 15;
    int kt    = (flat >> 13) & 7;
    int rest  = flat >> 16;                        // 0..5
    int part  = rest % 3;
    int layer = rest / 3;
    int k = kt * 32 + (lane >> 4) * 8 + j;
    int n = ntile * 16 + (lane & 15);
    const float* W = layer ? W_h2 : W_h;           // row-major [n][k] = W[n*256+k]
    float w = W[n * HH + k];
    __hip_bfloat16 h = __float2bfloat16(w);
    float r1 = w - __bfloat162float(h);
    __hip_bfloat16 m = __float2bfloat16(r1);
    float r2 = r1 - __bfloat162float(m);
    __hip_bfloat16 l = __float2bfloat16(r2);
    __hip_bfloat16 v = (part == 0) ? h : ((part == 1) ? m : l);
    WA[flat] = *reinterpret_cast<unsigned short*>(&v);
}

union U16x8 { uint4 u; bf16x8_t v; };

// Wave w computes n-tile w of one layer: D += sum_k A*B, kt ascending, parts 0,1,2
// at each kt — SAME accumulation order as R12-R14 -> bit-identical D.
// unroll 2: 6 A-loads in flight; kt remains a loop variable (no cross-t hoist/spill).
__device__ __forceinline__ void mfma_tile(const unsigned short* __restrict__ WA, int layer,
                                          const unsigned short* __restrict__ sbuf,
                                          int w, int lane, f32x4_t& D)
{
    const uint4* Wp = (const uint4*)WA + (size_t)layer * 3 * 8 * 16 * 64;
    const uint4* Bp = (const uint4*)sbuf;
#pragma unroll 2
    for (int kt = 0; kt < 8; ++kt) {
        U16x8 braw; braw.u = Bp[kt * 64 + lane];   // ds_read_b128, B-frag (spikes)
        uint4 a[3];
#pragma unroll
        for (int part = 0; part < 3; ++part)
            a[part] = Wp[((part * 8 + kt) * 16 + w) * 64 + lane];
#pragma unroll
        for (int part = 0; part < 3; ++part) {
            U16x8 ar; ar.u = a[part];
            D = __builtin_amdgcn_mfma_f32_16x16x32_bf16(ar.v, braw.v, D, 0, 0, 0);
        }
    }
}

__global__ __launch_bounds__(1024, 4) void snn_main_kernel(
    const float* __restrict__ x,
    const float* __restrict__ W_in, const float* __restrict__ b_in,
    const float* __restrict__ beta_in, const float* __restrict__ thr_in,
    const float* __restrict__ b_h, const float* __restrict__ beta_h, const float* __restrict__ thr_h,
    const float* __restrict__ b_h2, const float* __restrict__ beta_h2, const float* __restrict__ thr_h2,
    const float* __restrict__ W_out, const float* __restrict__ b_out, const float* __restrict__ beta_out,
    const unsigned short* __restrict__ WA, const float* __restrict__ emb,
    float* __restrict__ rec)
{
#pragma clang fp contract(off)   // all contraction EXPLICIT via fmaf
    const int tid = threadIdx.x;
    const int w = tid >> 6;       // wave 0..15 = n-tile
    const int lane = tid & 63;
    const int b = lane & 15;      // batch column (D col = lane&15)
    const int g = lane >> 4;      // row group   (D row = g*4+reg)
    const int b0 = blockIdx.x * BMb;

    __shared__ unsigned short sbuf1[8 * 64 * 8];   // B-frags spikes layer1 (8 KB)
    __shared__ unsigned short sbuf2[8 * 64 * 8];   // B-frags spikes layer2 (8 KB)
    __shared__ unsigned long long M3L[16][4];      // [ntile][reg] ballots of s3
    __shared__ float WoutS[2 * HH];
    __shared__ float4 PL1a[HH];   // {wi0, wi1, wi2, b_in}
    __shared__ float4 PL1b[HH];   // {bt1c, th1, -, -}
    __shared__ float4 PL2[HH];    // {b_h,  bt2c, th2, -}
    __shared__ float4 PL3[HH];    // {b_h2, bt3c, th3, -}

    if (tid < 512) WoutS[tid] = W_out[tid];
    if (tid < HH) {
        int n = tid;
        PL1a[n] = make_float4(W_in[n * 3], W_in[n * 3 + 1], W_in[n * 3 + 2], b_in[n]);
        PL1b[n] = make_float4(clip01f(beta_in[n]), thr_in[n], 0.f, 0.f);
        PL2[n]  = make_float4(b_h[n],  clip01f(beta_h[n]),  thr_h[n],  0.f);
        PL3[n]  = make_float4(b_h2[n], clip01f(beta_h2[n]), thr_h2[n], 0.f);
    }
    __syncthreads();

    // this thread's 4 neurons: n = w*16 + g*4 + r  (same as its D rows), batch b
    const int nb = w * 16 + g * 4;

    float m1[4], m2[4], m4[4];
#pragma unroll
    for (int r = 0; r < 4; ++r) { m1[r] = 0.f; m2[r] = 0.f; m4[r] = 0.f; }

    // spike -> B-frag LDS address (one b64 per thread):
    // k=n: kt2=w>>1, q=(w&1)*2+(g>>1), dst_lane=q*16+b, j0=(g&1)*4
    const int sb_off = (((w >> 1) * 64 + (((w & 1) * 2 + (g >> 1)) * 16 + b)) * 8 + (g & 1) * 4);

    // li_out walker state (wave 0, lanes 0..31): wb = batch, ooc = channel
    const int wb = lane & 15;
    const int ooc = (lane >> 4) & 1;
    float bto = clip01f(beta_out[ooc]);
    float bo = b_out[ooc];
    float m3s = 0.f;

    for (int t = 0; t < TT; ++t) {
        float et = emb[t];
        const float* xp = x + ((size_t)t * BB + b0 + b) * 3;
        float xe0 = xp[0] * et, xe1 = xp[1] * et, xe2 = xp[2] * et;  // rounded first

        // ---- layer 1: exact f32 chain + contracted LIF; spikes -> B-frag LDS ----
        {
            unsigned sp[4];
#pragma unroll
            for (int r = 0; r < 4; ++r) {
                int n = nb + r;
                float4 pa = PL1a[n];
                float4 pb = PL1b[n];
                float a1 = xe0 * pa.x;
                a1 = fmaf(xe1, pa.y, a1);
                a1 = fmaf(xe2, pa.z, a1);
                float cur = a1 + pa.w;
                float rf = ((m1[r] - pb.y) > 0.f) ? 1.f : 0.f;   // reset from PREVIOUS mem
                float mm = fmaf(pb.x, m1[r], cur);               // contracted: beta*m + cur
                mm = fmaf(-rf, pb.y, mm);                        // contracted: - reset*thr
                m1[r] = mm;
                sp[r] = ((mm - pb.y) > 0.f) ? 0x3F80u : 0u;      // bf16 1.0 / 0.0
            }
            *(uint2*)(sbuf1 + sb_off) = make_uint2(sp[0] | (sp[1] << 16), sp[2] | (sp[3] << 16));
        }
        __syncthreads();

        // ---- layer 2: MFMA tile w (3-part exact bf16 split), epilogue LIF ----
        {
            f32x4_t D = (f32x4_t){0.f, 0.f, 0.f, 0.f};
            mfma_tile(WA, 0, sbuf1, w, lane, D);
            unsigned sp[4];
#pragma unroll
            for (int r = 0; r < 4; ++r) {
                int n = nb + r;
                float4 p2 = PL2[n];
                float cur = D[r] + p2.x;
                float rf = ((m2[r] - p2.z) > 0.f) ? 1.f : 0.f;
                float mm = fmaf(p2.y, m2[r], cur);
                mm = fmaf(-rf, p2.z, mm);
                m2[r] = mm;
                sp[r] = ((mm - p2.z) > 0.f) ? 0x3F80u : 0u;
            }
            *(uint2*)(sbuf2 + sb_off) = make_uint2(sp[0] | (sp[1] << 16), sp[2] | (sp[3] << 16));
        }
        __syncthreads();

        // ---- layer 3: MFMA tile w, epilogue LIF -> ballots for li_out ----
        {
            f32x4_t D = (f32x4_t){0.f, 0.f, 0.f, 0.f};
            mfma_tile(WA, 1, sbuf2, w, lane, D);
#pragma unroll
            for (int r = 0; r < 4; ++r) {
                int n = nb + r;
                float4 p3 = PL3[n];
                float cur = D[r] + p3.x;
                float rf = ((m4[r] - p3.z) > 0.f) ? 1.f : 0.f;
                float mm = fmaf(p3.y, m4[r], cur);
                mm = fmaf(-rf, p3.z, mm);
                m4[r] = mm;
                bool s3 = (mm - p3.z) > 0.f;
                unsigned long long mk = __ballot(s3);   // bit at lane = (g<<4)|b
                if (lane == 0) M3L[w][r] = mk;
            }
        }
        __syncthreads();

        // ---- li_out (R8-exact): sequential k=0..255 chain; contracted m3 update ----
        if (w == 0 && lane < 32) {
            float p = 0.f;
            for (int k = 0; k < HH; ++k) {
                int ww = k >> 4, gg = (k >> 2) & 3, reg = k & 3;
                unsigned long long word = M3L[ww][reg];
                unsigned w32 = (gg < 2) ? (unsigned)word : (unsigned)(word >> 32);
                int sh = ((gg & 1) << 4) | wb;
                unsigned bit = (w32 >> sh) & 1u;
                float wv = WoutS[ooc * HH + k];
                p = p + (bit ? wv : 0.f);           // skip-zero == exact chain
            }
            float mm3 = fmaf(bto, m3s, p);
            mm3 = mm3 + bo;
            m3s = mm3;
            float spk = ((m3s - 1.0f) > 0.f) ? 1.f : 0.f;
            float om3 = __shfl_xor(m3s, 16, 64);
            float osp = __shfl_xor(spk, 16, 64);
            if (lane < 16) {
                *(float4*)(rec + ((size_t)t * BB + b0 + wb) * 4) =
                    make_float4(spk, osp, m3s, om3);
            }
        }
        // M3L rewritten only after next BAR3; wave0 finishes walker before its next BAR1.
    }
}

// out[r,o] = (ascending-k fma dot) + b_pred[o]
__global__ __launch_bounds__(256) void pred_kernel(
    const float* __restrict__ rec, const float* __restrict__ W_pred,
    const float* __restrict__ b_pred, float* __restrict__ out)
{
#pragma clang fp contract(off)
    int r = blockIdx.x * 256 + threadIdx.x;   // 0..4095
    const float* f = rec + (size_t)r * 256;
    float a0 = 0.f, a1 = 0.f;
#pragma unroll 4
    for (int c = 0; c < 256; ++c) {
        float v = f[c];
        a0 = fmaf(v, W_pred[c], a0);
        a1 = fmaf(v, W_pred[256 + c], a1);
    }
    out[r * 2 + 0] = a0 + b_pred[0];
    out[r * 2 + 1] = a1 + b_pred[1];
}

extern "C" void kernel_launch(void* const* d_in, const int* in_sizes, int n_in,
                              void* d_out, int out_size, void* d_ws, size_t ws_size,
                              hipStream_t stream)
{
    const float* x        = (const float*)d_in[0];
    const float* W_in     = (const float*)d_in[1];
    const float* b_in     = (const float*)d_in[2];
    const float* beta_in  = (const float*)d_in[3];
    const float* thr_in   = (const float*)d_in[4];
    const float* W_h      = (const float*)d_in[5];
    const float* b_h      = (const float*)d_in[6];
    const float* beta_h   = (const float*)d_in[7];
    const float* thr_h    = (const float*)d_in[8];
    const float* W_h2     = (const float*)d_in[9];
    const float* b_h2     = (const float*)d_in[10];
    const float* beta_h2  = (const float*)d_in[11];
    const float* thr_h2   = (const float*)d_in[12];
    const float* W_out    = (const float*)d_in[13];
    const float* b_out    = (const float*)d_in[14];
    const float* beta_out = (const float*)d_in[15];
    const float* W_pred   = (const float*)d_in[16];
    const float* b_pred   = (const float*)d_in[17];

    char* ws = (char*)d_ws;
    unsigned short* WA = (unsigned short*)(ws + WS_WA_B);
    float* emb = (float*)(ws + WS_EMB_B);
    float* rec = (float*)(ws + WS_REC_B);

    split_weights_kernel<<<1536, 256, 0, stream>>>(W_h, W_h2, WA);
    setup_emb_kernel<<<1, 64, 0, stream>>>(emb);

    snn_main_kernel<<<NBLK, 1024, 0, stream>>>(
        x, W_in, b_in, beta_in, thr_in,
        b_h, beta_h, thr_h,
        b_h2, beta_h2, thr_h2,
        W_out, b_out, beta_out,
        WA, emb, rec);

    pred_kernel<<<BB / 256, 256, 0, stream>>>(rec, W_pred, b_pred, (float*)d_out);
}